// Round 6
// baseline (277.311 us; speedup 1.0000x reference)
//
#include <hip/hip_runtime.h>
#include <hip/hip_bf16.h>
#include <hip/hip_cooperative_groups.h>
#include <stdint.h>

namespace cg = cooperative_groups;

// B=2, L=256, CB=64, D=512, H=8, HD=64. BI = B*L = 512.
// Single cooperative kernel, 512 blocks x 256 threads, 5 phases / 4 grid syncs:
//   P0 (blocks<128): MkT[hc][e] bf16 (pre-scaled 0.125), MvT[f][hc] bf16,
//                    Cb[hc] f32 (pre-scaled), bvoP[8][512] f32   (MFMA)
//   P1: qkP[z] = x @ Mk_s (+Cb at z=0), split-K=4, tile 32x64
//   P2: per (b,i): pair staged ONCE to LDS -> scores MFMA -> softmax (no max-sub)
//       -> wp MFMA -> shfl-pack bf16 store
//   P3: GP[z] = wp @ Mv, split-K=4, tile 32x64
//   P4: LayerNorm(sum_z GP + bo + sum_h bvoP + x)
// Fallback: the same 5 phases as separate kernels if cooperative launch fails.
//
// ws (float offsets): MkT@0(131072 u32) MvT@131072 Cb@262144 bvoP@262656
//   qkP@266752 (4x262144 f32, reused as GP) wp@1315328 (131072 u32)

using u32   = unsigned int;
using s8bf  = __attribute__((ext_vector_type(8))) short;
using f32x4 = __attribute__((ext_vector_type(4))) float;

union U4 { uint4 u; s8bf v; };

__device__ __forceinline__ u32 pack2(float a, float b) {
  __hip_bfloat162 h2 = __float22bfloat162_rn(make_float2(a, b));
  union { __hip_bfloat162 h; u32 u; } cv; cv.h = h2; return cv.u;
}
__device__ __forceinline__ ushort bf16r(float f) {
  u32 u = __float_as_uint(f);
  return (ushort)((u + 0x7fffu + ((u >> 16) & 1u)) >> 16);
}
__device__ __forceinline__ float ubf(ushort s) {
  return __uint_as_float(((u32)s) << 16);
}

// ---------------- phase bodies (shared by fused + fallback) ----------------

struct SmemK0 { ushort LA[64 * 72]; ushort LB[64 * 72]; float bvec[64]; };
struct SmemG  { ushort As[32 * 136]; ushort Bs[64 * 136]; };
struct SmemK2 { u32 PuU[256 * 36]; u32 PtU[64 * 132]; float redz[16][4]; };
struct SmemK4 { float red[2][4]; };
union SmemAll { SmemK0 k0; SmemG g; SmemK2 k2; SmemK4 k4; };

__device__ __forceinline__ void phase_k0(
    SmemK0& sm, int bid, int t,
    const float* __restrict__ Wq, const float* __restrict__ bq,
    const float* __restrict__ Wk, const float* __restrict__ Wv,
    const float* __restrict__ Wo, const float* __restrict__ bv,
    u32* __restrict__ MkT, u32* __restrict__ MvT,
    float* __restrict__ Cb, float* __restrict__ bvoP) {
  const bool isMk = bid < 64;
  const int sub = isMk ? bid : bid - 64;
  const int h = sub >> 3;
  const int tile = (sub & 7) * 64;

  { // LA: 64 rows x 64 d, fp32 -> bf16
    int row = t >> 2, q = t & 3;
    const float* Arow = isMk ? (Wq + (size_t)(tile + row) * 512 + h * 64)
                             : (Wv + (size_t)row * 512 + h * 64);
    #pragma unroll
    for (int i = 0; i < 4; ++i) {
      int d0 = q * 4 + i * 16;
      float4 v = *(const float4*)(Arow + d0);
      *(uint2*)&sm.LA[row * 72 + d0] = make_uint2(pack2(v.x, v.y), pack2(v.z, v.w));
    }
  }
  if (isMk) {
    int row = t >> 2, q = t & 3;
    const float* Brow = Wk + (size_t)row * 512 + h * 64;
    #pragma unroll
    for (int i = 0; i < 4; ++i) {
      int d0 = q * 4 + i * 16;
      float4 v = *(const float4*)(Brow + d0);
      *(uint2*)&sm.LB[row * 72 + d0] = make_uint2(pack2(v.x, v.y), pack2(v.z, v.w));
    }
  } else {      // LB = Wo^T rows f
    int d = t >> 2, q = t & 3;
    const float* Brow = Wo + (size_t)(h * 64 + d) * 512 + tile;
    #pragma unroll
    for (int i = 0; i < 4; ++i) {
      int f0 = q * 4 + i * 16;
      float4 v = *(const float4*)(Brow + f0);
      sm.LB[(f0 + 0) * 72 + d] = bf16r(v.x);
      sm.LB[(f0 + 1) * 72 + d] = bf16r(v.y);
      sm.LB[(f0 + 2) * 72 + d] = bf16r(v.z);
      sm.LB[(f0 + 3) * 72 + d] = bf16r(v.w);
    }
  }
  if (t < 16) {
    const float* bsrc = isMk ? bq : bv;
    float4 v = *(const float4*)&bsrc[h * 64 + t * 4];
    sm.bvec[t * 4 + 0] = v.x; sm.bvec[t * 4 + 1] = v.y;
    sm.bvec[t * 4 + 2] = v.z; sm.bvec[t * 4 + 3] = v.w;
  }
  __syncthreads();

  const int lane = t & 63, w = t >> 6;
  const int lr = lane & 15, lg = lane >> 4;
  f32x4 acc[4] = {};
  #pragma unroll
  for (int kk = 0; kk < 2; ++kk) {
    U4 a; a.u = *(const uint4*)&sm.LA[(w * 16 + lr) * 72 + kk * 32 + lg * 8];
    #pragma unroll
    for (int nt = 0; nt < 4; ++nt) {
      U4 b; b.u = *(const uint4*)&sm.LB[(nt * 16 + lr) * 72 + kk * 32 + lg * 8];
      acc[nt] = __builtin_amdgcn_mfma_f32_16x16x32_bf16(a.v, b.v, acc[nt], 0, 0, 0);
    }
  }
  if (isMk) {
    #pragma unroll
    for (int nt = 0; nt < 4; ++nt) {
      int hc = h * 64 + nt * 16 + lr;
      int e0 = tile + w * 16 + lg * 4;
      uint2 o = make_uint2(pack2(acc[nt][0] * 0.125f, acc[nt][1] * 0.125f),
                           pack2(acc[nt][2] * 0.125f, acc[nt][3] * 0.125f));
      *(uint2*)&MkT[(size_t)hc * 256 + (e0 >> 1)] = o;
    }
    if ((sub & 7) == 0 && t < 64) {
      float s = 0.f;
      #pragma unroll 16
      for (int d = 0; d < 64; ++d) s += sm.bvec[d] * ubf(sm.LB[t * 72 + d]);
      Cb[h * 64 + t] = s * 0.125f;
    }
  } else {
    #pragma unroll
    for (int nt = 0; nt < 4; ++nt) {
      int f = tile + nt * 16 + lr;
      int hc0 = h * 64 + w * 16 + lg * 4;
      uint2 o = make_uint2(pack2(acc[nt][0], acc[nt][1]),
                           pack2(acc[nt][2], acc[nt][3]));
      *(uint2*)&MvT[(size_t)f * 256 + (hc0 >> 1)] = o;
    }
    if (t < 64) {
      float s = 0.f;
      #pragma unroll 16
      for (int d = 0; d < 64; ++d) s += sm.bvec[d] * ubf(sm.LB[t * 72 + d]);
      bvoP[h * 512 + tile + t] = s;
    }
  }
}

__device__ __forceinline__ void phase_g1(
    SmemG& sm, int n0, int m0, int kz, int t,
    const float* __restrict__ x, const u32* __restrict__ MkT,
    const float* __restrict__ Cb, float* __restrict__ qkP) {
  { // A: 32 rows x 128 k fp32 -> bf16
    int row = t >> 3, q = t & 7;
    const float* xp = x + (size_t)(m0 + row) * 512 + kz * 128;
    #pragma unroll
    for (int i = 0; i < 4; ++i) {
      int d0 = q * 4 + i * 32;
      float4 v = *(const float4*)(xp + d0);
      *(uint2*)&sm.As[row * 136 + d0] = make_uint2(pack2(v.x, v.y), pack2(v.z, v.w));
    }
  }
  {
    int row = t >> 2, q = t & 3;
    const uint4* B4 = (const uint4*)MkT + (size_t)(n0 + row) * 64 + kz * 16;
    #pragma unroll
    for (int i = 0; i < 4; ++i) {
      uint4 v = B4[q * 4 + i];
      *(uint4*)&sm.Bs[row * 136 + q * 32 + i * 8] = v;
    }
  }
  __syncthreads();
  const int lane = t & 63, w = t >> 6;
  const int lr = lane & 15, lg = lane >> 4;
  const int mh = w & 1, nh = w >> 1;
  f32x4 acc[2] = {};
  #pragma unroll
  for (int kk = 0; kk < 4; ++kk) {
    U4 a; a.u = *(const uint4*)&sm.As[(mh * 16 + lr) * 136 + kk * 32 + lg * 8];
    #pragma unroll
    for (int nt = 0; nt < 2; ++nt) {
      U4 b; b.u = *(const uint4*)&sm.Bs[(nh * 32 + nt * 16 + lr) * 136 + kk * 32 + lg * 8];
      acc[nt] = __builtin_amdgcn_mfma_f32_16x16x32_bf16(a.v, b.v, acc[nt], 0, 0, 0);
    }
  }
  #pragma unroll
  for (int nt = 0; nt < 2; ++nt) {
    int n = n0 + nh * 32 + nt * 16 + lr;
    float cb = (kz == 0) ? Cb[n] : 0.f;
    #pragma unroll
    for (int r = 0; r < 4; ++r)
      qkP[(size_t)kz * 262144 + (size_t)(m0 + mh * 16 + lg * 4 + r) * 512 + n] =
          acc[nt][r] + cb;
  }
}

__device__ __forceinline__ void phase_g2(
    SmemG& sm, int n0, int m0, int kz, int t,
    const u32* __restrict__ wp, const u32* __restrict__ MvT,
    float* __restrict__ GP) {
  {
    int row = t >> 3, q = t & 7;
    const uint4* A4 = (const uint4*)wp + (size_t)(m0 + row) * 64 + kz * 16;
    #pragma unroll
    for (int i = 0; i < 2; ++i) {
      uint4 v = A4[q * 2 + i];
      *(uint4*)&sm.As[row * 136 + q * 16 + i * 8] = v;
    }
  }
  {
    int row = t >> 2, q = t & 3;
    const uint4* B4 = (const uint4*)MvT + (size_t)(n0 + row) * 64 + kz * 16;
    #pragma unroll
    for (int i = 0; i < 4; ++i) {
      uint4 v = B4[q * 4 + i];
      *(uint4*)&sm.Bs[row * 136 + q * 32 + i * 8] = v;
    }
  }
  __syncthreads();
  const int lane = t & 63, w = t >> 6;
  const int lr = lane & 15, lg = lane >> 4;
  const int mh = w & 1, nh = w >> 1;
  f32x4 acc[2] = {};
  #pragma unroll
  for (int kk = 0; kk < 4; ++kk) {
    U4 a; a.u = *(const uint4*)&sm.As[(mh * 16 + lr) * 136 + kk * 32 + lg * 8];
    #pragma unroll
    for (int nt = 0; nt < 2; ++nt) {
      U4 b; b.u = *(const uint4*)&sm.Bs[(nh * 32 + nt * 16 + lr) * 136 + kk * 32 + lg * 8];
      acc[nt] = __builtin_amdgcn_mfma_f32_16x16x32_bf16(a.v, b.v, acc[nt], 0, 0, 0);
    }
  }
  #pragma unroll
  for (int nt = 0; nt < 2; ++nt) {
    int n = n0 + nh * 32 + nt * 16 + lr;
    #pragma unroll
    for (int r = 0; r < 4; ++r)
      GP[(size_t)kz * 262144 + (size_t)(m0 + mh * 16 + lg * 4 + r) * 512 + n] = acc[nt][r];
  }
}

__device__ __forceinline__ void phase_k2(
    SmemK2& sm, int bi, int t,
    const float* __restrict__ pair, const float* __restrict__ qkP,
    u32* __restrict__ wpg) {
  const int lane = t & 63, w = t >> 6;
  const int lr = lane & 15, lg = lane >> 4;
  const float* pr = pair + (size_t)bi * 16384;

  #pragma unroll
  for (int r = 0; r < 8; ++r) {
    int task = t + 256 * r;
    int jp = task >> 4, cq = task & 15;
    const float* p0 = pr + (size_t)(2 * jp) * 64 + cq * 4;
    float4 a = *(const float4*)p0;
    float4 b = *(const float4*)(p0 + 64);
    *(uint2*)&sm.PuU[(2 * jp) * 36 + cq * 2]     = make_uint2(pack2(a.x, a.y), pack2(a.z, a.w));
    *(uint2*)&sm.PuU[(2 * jp + 1) * 36 + cq * 2] = make_uint2(pack2(b.x, b.y), pack2(b.z, b.w));
    int c = cq * 4;
    int col = jp ^ ((cq & 7) << 2);
    sm.PtU[(c + 0) * 132 + col] = pack2(a.x, b.x);
    sm.PtU[(c + 1) * 132 + col] = pack2(a.y, b.y);
    sm.PtU[(c + 2) * 132 + col] = pack2(a.z, b.z);
    sm.PtU[(c + 3) * 132 + col] = pack2(a.w, b.w);
  }

  U4 bq0, bq1;
  bq0.u = make_uint4(0, 0, 0, 0); bq1.u = make_uint4(0, 0, 0, 0);
  if (lr < 8) {
    const float* q0 = qkP + (size_t)bi * 512 + lr * 64 + lg * 8;
    float4 a0 = *(const float4*)q0,        a1 = *(const float4*)(q0 + 4);
    float4 a2 = *(const float4*)(q0 + 32), a3 = *(const float4*)(q0 + 36);
    #pragma unroll
    for (int z = 1; z < 4; ++z) {
      const float* qz = q0 + (size_t)z * 262144;
      float4 c0 = *(const float4*)qz,        c1 = *(const float4*)(qz + 4);
      float4 c2 = *(const float4*)(qz + 32), c3 = *(const float4*)(qz + 36);
      a0.x += c0.x; a0.y += c0.y; a0.z += c0.z; a0.w += c0.w;
      a1.x += c1.x; a1.y += c1.y; a1.z += c1.z; a1.w += c1.w;
      a2.x += c2.x; a2.y += c2.y; a2.z += c2.z; a2.w += c2.w;
      a3.x += c3.x; a3.y += c3.y; a3.z += c3.z; a3.w += c3.w;
    }
    bq0.u = make_uint4(pack2(a0.x, a0.y), pack2(a0.z, a0.w),
                       pack2(a1.x, a1.y), pack2(a1.z, a1.w));
    bq1.u = make_uint4(pack2(a2.x, a2.y), pack2(a2.z, a2.w),
                       pack2(a3.x, a3.y), pack2(a3.z, a3.w));
  }
  __syncthreads();

  f32x4 sc[4];
  #pragma unroll
  for (int jt = 0; jt < 4; ++jt) {
    int j0 = w * 64 + jt * 16;
    U4 a0, a1;
    a0.u = *(const uint4*)&sm.PuU[(j0 + lr) * 36 + lg * 4];
    a1.u = *(const uint4*)&sm.PuU[(j0 + lr) * 36 + 16 + lg * 4];
    f32x4 z = {0.f, 0.f, 0.f, 0.f};
    z = __builtin_amdgcn_mfma_f32_16x16x32_bf16(a0.v, bq0.v, z, 0, 0, 0);
    z = __builtin_amdgcn_mfma_f32_16x16x32_bf16(a1.v, bq1.v, z, 0, 0, 0);
    sc[jt] = z;
  }

  float ev[4][4];
  float es = 0.f;
  #pragma unroll
  for (int jt = 0; jt < 4; ++jt)
    #pragma unroll
    for (int r = 0; r < 4; ++r) { ev[jt][r] = __expf(sc[jt][r]); es += ev[jt][r]; }
  es += __shfl_xor(es, 16, 64);
  es += __shfl_xor(es, 32, 64);
  if (lane < 16) sm.redz[lr][w] = es;
  __syncthreads();
  float4 zr = *(const float4*)&sm.redz[lr][0];
  float rz = __builtin_amdgcn_rcpf(zr.x + zr.y + zr.z + zr.w);
  ushort* wb = (ushort*)sm.PuU;
  #pragma unroll
  for (int jt = 0; jt < 4; ++jt) {
    int j0 = w * 64 + jt * 16 + lg * 4;
    uint2 o = make_uint2(pack2(ev[jt][0] * rz, ev[jt][1] * rz),
                         pack2(ev[jt][2] * rz, ev[jt][3] * rz));
    *(uint2*)&wb[lr * 264 + j0] = o;
  }
  __syncthreads();

  f32x4 wacc = {0.f, 0.f, 0.f, 0.f};
  const int c = w * 16 + lr;
  const int cswz = (c >> 2) & 7;
  #pragma unroll
  for (int ks = 0; ks < 8; ++ks) {
    U4 a; a.u = *(const uint4*)&wb[lr * 264 + ks * 32 + lg * 8];
    int g = ks * 4 + lg;
    U4 b; b.u = *(const uint4*)&sm.PtU[c * 132 + ((g ^ cswz) << 2)];
    wacc = __builtin_amdgcn_mfma_f32_16x16x32_bf16(a.v, b.v, wacc, 0, 0, 0);
  }
  float prt[4];
  #pragma unroll
  for (int r = 0; r < 4; ++r) prt[r] = __shfl_xor(wacc[r], 1, 64);
  if (lane < 32 && (lane & 1) == 0) {
    #pragma unroll
    for (int r = 0; r < 4; ++r) {
      int h = lg * 4 + r;
      wpg[(size_t)bi * 256 + h * 32 + (c >> 1)] = pack2(wacc[r], prt[r]);
    }
  }
}

__device__ __forceinline__ void phase_k4(
    SmemK4& sm, int bi, int t,
    const float* __restrict__ GP, const float* __restrict__ bvoP,
    const float* __restrict__ bo, const float* __restrict__ x,
    const float* __restrict__ gamma, const float* __restrict__ beta,
    float* __restrict__ out) {
  const int f = t * 2;
  const size_t base = (size_t)bi * 512 + f;
  float2 y2 = *(const float2*)&GP[base];
  #pragma unroll
  for (int z = 1; z < 4; ++z) {
    float2 g = *(const float2*)&GP[(size_t)z * 262144 + base];
    y2.x += g.x; y2.y += g.y;
  }
  float2 xv = *(const float2*)&x[base];
  float2 bv2 = *(const float2*)&bo[f];
  y2.x += xv.x + bv2.x; y2.y += xv.y + bv2.y;
  #pragma unroll
  for (int h = 0; h < 8; ++h) {
    float2 bp = *(const float2*)&bvoP[h * 512 + f];
    y2.x += bp.x; y2.y += bp.y;
  }
  float s = y2.x + y2.y;
  float q = y2.x * y2.x + y2.y * y2.y;
  for (int o = 32; o; o >>= 1) { s += __shfl_xor(s, o, 64); q += __shfl_xor(q, o, 64); }
  const int wv = t >> 6, lane = t & 63;
  if (lane == 0) { sm.red[0][wv] = s; sm.red[1][wv] = q; }
  __syncthreads();
  float S = sm.red[0][0] + sm.red[0][1] + sm.red[0][2] + sm.red[0][3];
  float Qs = sm.red[1][0] + sm.red[1][1] + sm.red[1][2] + sm.red[1][3];
  float mu = S * (1.f / 512.f);
  float var = Qs * (1.f / 512.f) - mu * mu;
  float rstd = rsqrtf(var + 1e-5f);
  float2 gm = *(const float2*)&gamma[f];
  float2 bt = *(const float2*)&beta[f];
  float2 o2;
  o2.x = (y2.x - mu) * rstd * gm.x + bt.x;
  o2.y = (y2.y - mu) * rstd * gm.y + bt.y;
  *(float2*)&out[base] = o2;
}

// ---------------- fused cooperative kernel ----------------
__global__ __launch_bounds__(256, 2) void k_fused(
    const float* __restrict__ x, const float* __restrict__ pair,
    const float* __restrict__ Wq, const float* __restrict__ bq,
    const float* __restrict__ Wk, const float* __restrict__ Wv,
    const float* __restrict__ bv, const float* __restrict__ Wo,
    const float* __restrict__ bo, const float* __restrict__ gamma,
    const float* __restrict__ beta,
    u32* __restrict__ MkT, u32* __restrict__ MvT,
    float* __restrict__ Cb, float* __restrict__ bvoP,
    float* __restrict__ qkP, u32* __restrict__ wp,
    float* __restrict__ out) {
  __shared__ SmemAll sm;
  cg::grid_group grid = cg::this_grid();
  const int bid = blockIdx.x;
  const int t = threadIdx.x;

  if (bid < 128)
    phase_k0(sm.k0, bid, t, Wq, bq, Wk, Wv, Wo, bv, MkT, MvT, Cb, bvoP);
  grid.sync();

  phase_g1(sm.g, (bid & 7) * 64, ((bid >> 3) & 15) * 32, bid >> 7, t, x, MkT, Cb, qkP);
  grid.sync();

  phase_k2(sm.k2, bid, t, pair, qkP, wp);
  grid.sync();

  phase_g2(sm.g, (bid & 7) * 64, ((bid >> 3) & 15) * 32, bid >> 7, t, wp, MvT, qkP);
  grid.sync();

  phase_k4(sm.k4, bid, t, qkP, bvoP, bo, x, gamma, beta, out);
}

// ---------------- fallback standalone kernels ----------------
__global__ __launch_bounds__(256) void k0_prep(
    const float* __restrict__ Wq, const float* __restrict__ bq,
    const float* __restrict__ Wk, const float* __restrict__ Wv,
    const float* __restrict__ Wo, const float* __restrict__ bv,
    u32* __restrict__ MkT, u32* __restrict__ MvT,
    float* __restrict__ Cb, float* __restrict__ bvoP) {
  __shared__ SmemK0 sm;
  phase_k0(sm, blockIdx.x, threadIdx.x, Wq, bq, Wk, Wv, Wo, bv, MkT, MvT, Cb, bvoP);
}
__global__ __launch_bounds__(256) void k_g1(
    const float* __restrict__ x, const u32* __restrict__ MkT,
    const float* __restrict__ Cb, float* __restrict__ qkP) {
  __shared__ SmemG sm;
  phase_g1(sm, blockIdx.x * 64, blockIdx.y * 32, blockIdx.z, threadIdx.x, x, MkT, Cb, qkP);
}
__global__ __launch_bounds__(256) void k2_attn(
    const float* __restrict__ pair, const float* __restrict__ qkP,
    u32* __restrict__ wpg) {
  __shared__ SmemK2 sm;
  phase_k2(sm, blockIdx.x, threadIdx.x, pair, qkP, wpg);
}
__global__ __launch_bounds__(256) void k_g2(
    const u32* __restrict__ wp, const u32* __restrict__ MvT,
    float* __restrict__ GP) {
  __shared__ SmemG sm;
  phase_g2(sm, blockIdx.x * 64, blockIdx.y * 32, blockIdx.z, threadIdx.x, wp, MvT, GP);
}
__global__ __launch_bounds__(256) void k4_ln(
    const float* __restrict__ GP, const float* __restrict__ bvoP,
    const float* __restrict__ bo, const float* __restrict__ x,
    const float* __restrict__ gamma, const float* __restrict__ beta,
    float* __restrict__ out) {
  __shared__ SmemK4 sm;
  phase_k4(sm, blockIdx.x, threadIdx.x, GP, bvoP, bo, x, gamma, beta, out);
}

extern "C" void kernel_launch(void* const* d_in, const int* in_sizes, int n_in,
                              void* d_out, int out_size, void* d_ws, size_t ws_size,
                              hipStream_t stream) {
  (void)in_sizes; (void)n_in; (void)out_size; (void)ws_size;
  const float* x     = (const float*)d_in[0];
  const float* pair  = (const float*)d_in[1];
  const float* Wq    = (const float*)d_in[2];
  const float* bq    = (const float*)d_in[3];
  const float* Wk    = (const float*)d_in[4];
  // d_in[5] = bk: Q.bk constant over j -> cancels in softmax
  const float* Wv    = (const float*)d_in[6];
  const float* bv    = (const float*)d_in[7];
  const float* Wo    = (const float*)d_in[8];
  const float* bo    = (const float*)d_in[9];
  const float* gamma = (const float*)d_in[10];
  const float* beta  = (const float*)d_in[11];

  float* ws   = (float*)d_ws;
  u32* MkT    = (u32*)ws;
  u32* MvT    = (u32*)ws + 131072;
  float* Cb   = ws + 262144;
  float* bvoP = ws + 262656;
  float* qkP  = ws + 266752;              // 4 slices; reused as GP
  u32* wp     = (u32*)(ws + 1315328);
  float* outp = (float*)d_out;

  void* args[] = {
    (void*)&x, (void*)&pair, (void*)&Wq, (void*)&bq, (void*)&Wk, (void*)&Wv,
    (void*)&bv, (void*)&Wo, (void*)&bo, (void*)&gamma, (void*)&beta,
    (void*)&MkT, (void*)&MvT, (void*)&Cb, (void*)&bvoP, (void*)&qkP,
    (void*)&wp, (void*)&outp
  };
  hipError_t err = hipLaunchCooperativeKernel(
      (const void*)k_fused, dim3(512), dim3(256), args, 0, stream);
  if (err != hipSuccess) {
    // fallback: 5 separate launches (identical math)
    k0_prep<<<128, 256, 0, stream>>>(Wq, bq, Wk, Wv, Wo, bv, MkT, MvT, Cb, bvoP);
    k_g1<<<dim3(8, 16, 4), 256, 0, stream>>>(x, MkT, Cb, qkP);
    k2_attn<<<512, 256, 0, stream>>>(pair, qkP, wp);
    k_g2<<<dim3(8, 16, 4), 256, 0, stream>>>(wp, MvT, qkP);
    k4_ln<<<512, 256, 0, stream>>>(qkP, bvoP, bo, x, gamma, beta, outp);
  }
}

// Round 7
// 74.487 us; speedup vs baseline: 3.7230x; 3.7230x over previous
//
#include <hip/hip_runtime.h>
#include <hip/hip_bf16.h>
#include <stdint.h>

// B=2, L=256, CB=64, D=512, H=8, HD=64. BI = 512.
// 3-launch pipeline (launch boundary = the cheap sync; grid.sync measured 65us -> dead):
//  L1 (578 blocks):
//    bid<512: self-contained qk tile: compute Mk_sub = Wq_sub.Wk^T (MFMA, in LDS,
//             scaled 0.125) + Cb_sub in-block, then qk = x @ Mk_sub (+Cb at kz=0).
//             grid map: h=bid&7 (64 hc cols), m=((bid>>3)&15)*32 bi rows, kz=bid>>7 (e 128).
//    512..575: MvT[f][hc] = (Wv@Wo per head)^T bf16 (MFMA)
//    576..577: bvoSum[f] = bv@Wo + bo (f32)
//  L2: K2 (unchanged round-5 body): pair staged once -> scores MFMA -> softmax
//      (no max-sub) -> wp MFMA -> shfl-pack bf16 wp
//  L3 (64 blocks x 8 rows): GEMM wp@MvT (A-frags direct-global, B-frags L2-stream)
//      + bvoSum + x residual + per-wave LayerNorm -> out. No GP traffic, no K4.
//
// ws (f32 offsets): MvT@0 (131072 u32) | bvoSum@131072 (512 f32) |
//   qkP@131584 (4x262144 f32) | wp@1180160 (131072 u32)

using u32   = unsigned int;
using s8bf  = __attribute__((ext_vector_type(8))) short;
using f32x4 = __attribute__((ext_vector_type(4))) float;

union U4 { uint4 u; s8bf v; };

__device__ __forceinline__ u32 pack2(float a, float b) {
  __hip_bfloat162 h2 = __float22bfloat162_rn(make_float2(a, b));
  union { __hip_bfloat162 h; u32 u; } cv; cv.h = h2; return cv.u;
}
__device__ __forceinline__ float ubf(ushort s) {
  return __uint_as_float(((u32)s) << 16);
}

// ---------------- L1 ----------------
struct SmemG1p {
  ushort Aq[128 * 72];    // Wq rows e(128) x d(64)
  ushort Bk[64 * 72];     // Wk rows c(64) x d(64)
  ushort MkS[64 * 136];   // Mk^T rows c(64) x e(128), scaled 0.125
  ushort Xs[32 * 136];    // x rows bi(32) x e(128)
  float  CbL[64];
};
struct SmemMv { ushort LA[64 * 72]; ushort LB[64 * 72]; };
union SmemL1 { SmemG1p g; SmemMv m; };

__global__ __launch_bounds__(256) void k_L1(
    const float* __restrict__ x,
    const float* __restrict__ Wq, const float* __restrict__ bq,
    const float* __restrict__ Wk, const float* __restrict__ Wv,
    const float* __restrict__ bv, const float* __restrict__ Wo,
    const float* __restrict__ bo,
    u32* __restrict__ MvT, float* __restrict__ bvoSum,
    float* __restrict__ qkP) {
  __shared__ SmemL1 sm;
  const int t = threadIdx.x;
  const int bid = blockIdx.x;
  const int lane = t & 63, w = t >> 6;
  const int lr = lane & 15, lg = lane >> 4;

  if (bid < 512) {
    // ---------- self-contained qk tile ----------
    const int h  = bid & 7;
    const int n0 = h * 64;
    const int m0 = ((bid >> 3) & 15) * 32;
    const int kz = bid >> 7;
    const int e0 = kz * 128;

    { // Aq: Wq rows e0..e0+127, cols h*64..h*64+63 -> bf16
      int row = t >> 1, q = t & 1;
      const float* src = Wq + (size_t)(e0 + row) * 512 + h * 64 + q * 32;
      #pragma unroll
      for (int i = 0; i < 4; ++i) {
        float4 a = *(const float4*)(src + i * 8);
        float4 b = *(const float4*)(src + i * 8 + 4);
        *(uint4*)&sm.g.Aq[row * 72 + q * 32 + i * 8] =
            make_uint4(pack2(a.x, a.y), pack2(a.z, a.w),
                       pack2(b.x, b.y), pack2(b.z, b.w));
      }
    }
    { // Bk: Wk rows c 0..63, cols h*64.. -> bf16
      int row = t >> 2, q = t & 3;
      const float* src = Wk + (size_t)row * 512 + h * 64 + q * 16;
      #pragma unroll
      for (int i = 0; i < 2; ++i) {
        float4 a = *(const float4*)(src + i * 8);
        float4 b = *(const float4*)(src + i * 8 + 4);
        *(uint4*)&sm.g.Bk[row * 72 + q * 16 + i * 8] =
            make_uint4(pack2(a.x, a.y), pack2(a.z, a.w),
                       pack2(b.x, b.y), pack2(b.z, b.w));
      }
    }
    { // Xs: x rows m0..m0+31, e-cols e0..e0+127 -> bf16
      int row = t >> 3, q = t & 7;
      const float* src = x + (size_t)(m0 + row) * 512 + e0 + q * 16;
      #pragma unroll
      for (int i = 0; i < 2; ++i) {
        float4 a = *(const float4*)(src + i * 8);
        float4 b = *(const float4*)(src + i * 8 + 4);
        *(uint4*)&sm.g.Xs[row * 136 + q * 16 + i * 8] =
            make_uint4(pack2(a.x, a.y), pack2(a.z, a.w),
                       pack2(b.x, b.y), pack2(b.z, b.w));
      }
    }
    __syncthreads();

    // Cb_sub (only needed by kz==0 blocks, cheap everywhere)
    if (t < 64) {
      float s = 0.f;
      #pragma unroll 16
      for (int d = 0; d < 64; ++d) s += bq[h * 64 + d] * ubf(sm.g.Bk[t * 72 + d]);
      sm.g.CbL[t] = s * 0.125f;
    }

    // Mk MFMA: M=e(128: 8 m-tiles), N=c(64: 4 n-tiles), K=d(64: 2 steps)
    f32x4 mkacc[2][4] = {};
    #pragma unroll
    for (int kk = 0; kk < 2; ++kk) {
      #pragma unroll
      for (int mt = 0; mt < 2; ++mt) {
        U4 a; a.u = *(const uint4*)&sm.g.Aq[((w * 2 + mt) * 16 + lr) * 72 + kk * 32 + lg * 8];
        #pragma unroll
        for (int nt = 0; nt < 4; ++nt) {
          U4 b; b.u = *(const uint4*)&sm.g.Bk[(nt * 16 + lr) * 72 + kk * 32 + lg * 8];
          mkacc[mt][nt] = __builtin_amdgcn_mfma_f32_16x16x32_bf16(a.v, b.v, mkacc[mt][nt], 0, 0, 0);
        }
      }
    }
    // store Mk^T (scaled) to MkS[c][e]
    #pragma unroll
    for (int mt = 0; mt < 2; ++mt)
      #pragma unroll
      for (int nt = 0; nt < 4; ++nt) {
        int c = nt * 16 + lr;
        int e = (w * 2 + mt) * 16 + lg * 4;
        *(u32*)&sm.g.MkS[c * 136 + e] =
            pack2(mkacc[mt][nt][0] * 0.125f, mkacc[mt][nt][1] * 0.125f);
        *(u32*)&sm.g.MkS[c * 136 + e + 2] =
            pack2(mkacc[mt][nt][2] * 0.125f, mkacc[mt][nt][3] * 0.125f);
      }
    __syncthreads();

    // qk MFMA: tile 32(bi) x 64(c), K=128(e)
    const int mh = w & 1, nh = w >> 1;
    f32x4 acc[2] = {};
    #pragma unroll
    for (int kk = 0; kk < 4; ++kk) {
      U4 a; a.u = *(const uint4*)&sm.g.Xs[(mh * 16 + lr) * 136 + kk * 32 + lg * 8];
      #pragma unroll
      for (int nt = 0; nt < 2; ++nt) {
        U4 b; b.u = *(const uint4*)&sm.g.MkS[(nh * 32 + nt * 16 + lr) * 136 + kk * 32 + lg * 8];
        acc[nt] = __builtin_amdgcn_mfma_f32_16x16x32_bf16(a.v, b.v, acc[nt], 0, 0, 0);
      }
    }
    #pragma unroll
    for (int nt = 0; nt < 2; ++nt) {
      int nl = nh * 32 + nt * 16 + lr;
      float cb = (kz == 0) ? sm.g.CbL[nl] : 0.f;
      #pragma unroll
      for (int r = 0; r < 4; ++r)
        qkP[(size_t)kz * 262144 + (size_t)(m0 + mh * 16 + lg * 4 + r) * 512 + n0 + nl] =
            acc[nt][r] + cb;
    }
    return;
  }

  if (bid < 576) {
    // ---------- MvT prep: Mv = Wv@Wo per head, store MvT[f][hc] bf16 ----------
    const int sub = bid - 512;
    const int h = sub >> 3;
    const int tile = (sub & 7) * 64;   // f-tile
    { // LA = Wv rows c(64) x d(64)
      int row = t >> 2, q = t & 3;
      const float* src = Wv + (size_t)row * 512 + h * 64 + q * 16;
      #pragma unroll
      for (int i = 0; i < 2; ++i) {
        float4 a = *(const float4*)(src + i * 8);
        float4 b = *(const float4*)(src + i * 8 + 4);
        *(uint4*)&sm.m.LA[row * 72 + q * 16 + i * 8] =
            make_uint4(pack2(a.x, a.y), pack2(a.z, a.w),
                       pack2(b.x, b.y), pack2(b.z, b.w));
      }
    }
    { // LB = Wo^T rows f(64) x d(64): read f-contig, scatter
      int d = t >> 2, q = t & 3;
      const float* src = Wo + (size_t)(h * 64 + d) * 512 + tile;
      #pragma unroll
      for (int i = 0; i < 4; ++i) {
        int f0 = q * 4 + i * 16;
        float4 v = *(const float4*)(src + f0);
        sm.m.LB[(f0 + 0) * 72 + d] = (ushort)(pack2(v.x, 0.f) & 0xffff);
        sm.m.LB[(f0 + 1) * 72 + d] = (ushort)(pack2(v.y, 0.f) & 0xffff);
        sm.m.LB[(f0 + 2) * 72 + d] = (ushort)(pack2(v.z, 0.f) & 0xffff);
        sm.m.LB[(f0 + 3) * 72 + d] = (ushort)(pack2(v.w, 0.f) & 0xffff);
      }
    }
    __syncthreads();
    f32x4 acc[4] = {};
    #pragma unroll
    for (int kk = 0; kk < 2; ++kk) {
      U4 a; a.u = *(const uint4*)&sm.m.LA[(w * 16 + lr) * 72 + kk * 32 + lg * 8];
      #pragma unroll
      for (int nt = 0; nt < 4; ++nt) {
        U4 b; b.u = *(const uint4*)&sm.m.LB[(nt * 16 + lr) * 72 + kk * 32 + lg * 8];
        acc[nt] = __builtin_amdgcn_mfma_f32_16x16x32_bf16(a.v, b.v, acc[nt], 0, 0, 0);
      }
    }
    // acc[nt][r]: m=c row = w*16+lg*4+r, n=f col = nt*16+lr -> MvT[f][hc], hc contig pack
    #pragma unroll
    for (int nt = 0; nt < 4; ++nt) {
      int f = tile + nt * 16 + lr;
      int hc0 = h * 64 + w * 16 + lg * 4;
      uint2 o = make_uint2(pack2(acc[nt][0], acc[nt][1]),
                           pack2(acc[nt][2], acc[nt][3]));
      *(uint2*)&MvT[(size_t)f * 256 + (hc0 >> 1)] = o;
    }
    return;
  }

  // ---------- bvoSum[f] = bv @ Wo + bo ----------
  {
    const int f = (bid - 576) * 256 + t;
    float s = bo[f];
    #pragma unroll 8
    for (int hd = 0; hd < 512; ++hd)
      s += bv[hd] * Wo[(size_t)hd * 512 + f];
    bvoSum[f] = s;
  }
}

// ---------------- L2: K2 (round-5 body, unchanged) ----------------
__global__ __launch_bounds__(256) void k2_attn(
    const float* __restrict__ pair, const float* __restrict__ qkP,
    u32* __restrict__ wpg) {
  __shared__ u32 PuU[256 * 36];
  __shared__ u32 PtU[64 * 132];
  __shared__ float redz[16][4];
  const int t = threadIdx.x, bi = blockIdx.x;
  const int lane = t & 63, w = t >> 6;
  const int lr = lane & 15, lg = lane >> 4;
  const float* pr = pair + (size_t)bi * 16384;

  #pragma unroll
  for (int r = 0; r < 8; ++r) {
    int task = t + 256 * r;
    int jp = task >> 4, cq = task & 15;
    const float* p0 = pr + (size_t)(2 * jp) * 64 + cq * 4;
    float4 a = *(const float4*)p0;
    float4 b = *(const float4*)(p0 + 64);
    *(uint2*)&PuU[(2 * jp) * 36 + cq * 2]     = make_uint2(pack2(a.x, a.y), pack2(a.z, a.w));
    *(uint2*)&PuU[(2 * jp + 1) * 36 + cq * 2] = make_uint2(pack2(b.x, b.y), pack2(b.z, b.w));
    int c = cq * 4;
    int col = jp ^ ((cq & 7) << 2);
    PtU[(c + 0) * 132 + col] = pack2(a.x, b.x);
    PtU[(c + 1) * 132 + col] = pack2(a.y, b.y);
    PtU[(c + 2) * 132 + col] = pack2(a.z, b.z);
    PtU[(c + 3) * 132 + col] = pack2(a.w, b.w);
  }

  U4 bq0, bq1;
  bq0.u = make_uint4(0, 0, 0, 0); bq1.u = make_uint4(0, 0, 0, 0);
  if (lr < 8) {
    const float* q0 = qkP + (size_t)bi * 512 + lr * 64 + lg * 8;
    float4 a0 = *(const float4*)q0,        a1 = *(const float4*)(q0 + 4);
    float4 a2 = *(const float4*)(q0 + 32), a3 = *(const float4*)(q0 + 36);
    #pragma unroll
    for (int z = 1; z < 4; ++z) {
      const float* qz = q0 + (size_t)z * 262144;
      float4 c0 = *(const float4*)qz,        c1 = *(const float4*)(qz + 4);
      float4 c2 = *(const float4*)(qz + 32), c3 = *(const float4*)(qz + 36);
      a0.x += c0.x; a0.y += c0.y; a0.z += c0.z; a0.w += c0.w;
      a1.x += c1.x; a1.y += c1.y; a1.z += c1.z; a1.w += c1.w;
      a2.x += c2.x; a2.y += c2.y; a2.z += c2.z; a2.w += c2.w;
      a3.x += c3.x; a3.y += c3.y; a3.z += c3.z; a3.w += c3.w;
    }
    bq0.u = make_uint4(pack2(a0.x, a0.y), pack2(a0.z, a0.w),
                       pack2(a1.x, a1.y), pack2(a1.z, a1.w));
    bq1.u = make_uint4(pack2(a2.x, a2.y), pack2(a2.z, a2.w),
                       pack2(a3.x, a3.y), pack2(a3.z, a3.w));
  }
  __syncthreads();

  f32x4 sc[4];
  #pragma unroll
  for (int jt = 0; jt < 4; ++jt) {
    int j0 = w * 64 + jt * 16;
    U4 a0, a1;
    a0.u = *(const uint4*)&PuU[(j0 + lr) * 36 + lg * 4];
    a1.u = *(const uint4*)&PuU[(j0 + lr) * 36 + 16 + lg * 4];
    f32x4 z = {0.f, 0.f, 0.f, 0.f};
    z = __builtin_amdgcn_mfma_f32_16x16x32_bf16(a0.v, bq0.v, z, 0, 0, 0);
    z = __builtin_amdgcn_mfma_f32_16x16x32_bf16(a1.v, bq1.v, z, 0, 0, 0);
    sc[jt] = z;
  }

  float ev[4][4];
  float es = 0.f;
  #pragma unroll
  for (int jt = 0; jt < 4; ++jt)
    #pragma unroll
    for (int r = 0; r < 4; ++r) { ev[jt][r] = __expf(sc[jt][r]); es += ev[jt][r]; }
  es += __shfl_xor(es, 16, 64);
  es += __shfl_xor(es, 32, 64);
  if (lane < 16) redz[lr][w] = es;
  __syncthreads();
  float4 zr = *(const float4*)&redz[lr][0];
  float rz = __builtin_amdgcn_rcpf(zr.x + zr.y + zr.z + zr.w);
  ushort* wb = (ushort*)PuU;
  #pragma unroll
  for (int jt = 0; jt < 4; ++jt) {
    int j0 = w * 64 + jt * 16 + lg * 4;
    uint2 o = make_uint2(pack2(ev[jt][0] * rz, ev[jt][1] * rz),
                         pack2(ev[jt][2] * rz, ev[jt][3] * rz));
    *(uint2*)&wb[lr * 264 + j0] = o;
  }
  __syncthreads();

  f32x4 wacc = {0.f, 0.f, 0.f, 0.f};
  const int c = w * 16 + lr;
  const int cswz = (c >> 2) & 7;
  #pragma unroll
  for (int ks = 0; ks < 8; ++ks) {
    U4 a; a.u = *(const uint4*)&wb[lr * 264 + ks * 32 + lg * 8];
    int g = ks * 4 + lg;
    U4 b; b.u = *(const uint4*)&PtU[c * 132 + ((g ^ cswz) << 2)];
    wacc = __builtin_amdgcn_mfma_f32_16x16x32_bf16(a.v, b.v, wacc, 0, 0, 0);
  }
  float prt[4];
  #pragma unroll
  for (int r = 0; r < 4; ++r) prt[r] = __shfl_xor(wacc[r], 1, 64);
  if (lane < 32 && (lane & 1) == 0) {
    #pragma unroll
    for (int r = 0; r < 4; ++r) {
      int h = lg * 4 + r;
      wpg[(size_t)bi * 256 + h * 32 + (c >> 1)] = pack2(wacc[r], prt[r]);
    }
  }
}

// ---------------- L3: GEMM(wp@Mv) + residual + LayerNorm ----------------
// 64 blocks x 8 bi-rows. A-frags direct from wp global (rows lr<8), B-frags
// streamed from MvT (L2). yF in LDS, per-wave LN (wave w owns rows 2w,2w+1).
__global__ __launch_bounds__(256) void k_L3(
    const u32* __restrict__ wp, const u32* __restrict__ MvT,
    const float* __restrict__ bvoSum, const float* __restrict__ x,
    const float* __restrict__ gamma, const float* __restrict__ beta,
    float* __restrict__ out) {
  __shared__ float yF[8 * 520];
  const int t = threadIdx.x;
  const int lane = t & 63, w = t >> 6;
  const int lr = lane & 15, lg = lane >> 4;
  const int bi0 = blockIdx.x * 8;

  f32x4 acc[8] = {};
  #pragma unroll
  for (int kk = 0; kk < 16; ++kk) {
    U4 a;
    if (lr < 8) a.u = *(const uint4*)&wp[(size_t)(bi0 + lr) * 256 + kk * 16 + lg * 4];
    else a.u = make_uint4(0, 0, 0, 0);
    #pragma unroll
    for (int nt = 0; nt < 8; ++nt) {
      int f = (w * 8 + nt) * 16 + lr;
      U4 b; b.u = *(const uint4*)&MvT[(size_t)f * 256 + kk * 16 + lg * 4];
      acc[nt] = __builtin_amdgcn_mfma_f32_16x16x32_bf16(a.v, b.v, acc[nt], 0, 0, 0);
    }
  }
  #pragma unroll
  for (int nt = 0; nt < 8; ++nt) {
    int f = (w * 8 + nt) * 16 + lr;
    #pragma unroll
    for (int r = 0; r < 4; ++r) {
      int row = lg * 4 + r;
      if (row < 8) yF[row * 520 + f] = acc[nt][r];
    }
  }
  __syncthreads();

  #pragma unroll
  for (int rr = 0; rr < 2; ++rr) {
    const int row = w * 2 + rr;
    const int bi = bi0 + row;
    const int f0 = lane * 8;
    float y[8];
    float s = 0.f, q = 0.f;
    #pragma unroll
    for (int i = 0; i < 8; i += 4) {
      float4 yv = *(const float4*)&yF[row * 520 + f0 + i];
      float4 xv = *(const float4*)&x[(size_t)bi * 512 + f0 + i];
      float4 bb = *(const float4*)&bvoSum[f0 + i];
      y[i + 0] = yv.x + xv.x + bb.x;
      y[i + 1] = yv.y + xv.y + bb.y;
      y[i + 2] = yv.z + xv.z + bb.z;
      y[i + 3] = yv.w + xv.w + bb.w;
      s += y[i] + y[i + 1] + y[i + 2] + y[i + 3];
      q += y[i] * y[i] + y[i + 1] * y[i + 1] + y[i + 2] * y[i + 2] + y[i + 3] * y[i + 3];
    }
    #pragma unroll
    for (int o = 32; o; o >>= 1) {
      s += __shfl_xor(s, o, 64);
      q += __shfl_xor(q, o, 64);
    }
    float mu = s * (1.f / 512.f);
    float var = q * (1.f / 512.f) - mu * mu;
    float rstd = rsqrtf(var + 1e-5f);
    #pragma unroll
    for (int i = 0; i < 8; i += 4) {
      float4 gm = *(const float4*)&gamma[f0 + i];
      float4 bt = *(const float4*)&beta[f0 + i];
      float4 o4;
      o4.x = (y[i + 0] - mu) * rstd * gm.x + bt.x;
      o4.y = (y[i + 1] - mu) * rstd * gm.y + bt.y;
      o4.z = (y[i + 2] - mu) * rstd * gm.z + bt.z;
      o4.w = (y[i + 3] - mu) * rstd * gm.w + bt.w;
      *(float4*)&out[(size_t)bi * 512 + f0 + i] = o4;
    }
  }
}

extern "C" void kernel_launch(void* const* d_in, const int* in_sizes, int n_in,
                              void* d_out, int out_size, void* d_ws, size_t ws_size,
                              hipStream_t stream) {
  (void)in_sizes; (void)n_in; (void)out_size; (void)ws_size;
  const float* x     = (const float*)d_in[0];
  const float* pair  = (const float*)d_in[1];
  const float* Wq    = (const float*)d_in[2];
  const float* bq    = (const float*)d_in[3];
  const float* Wk    = (const float*)d_in[4];
  // d_in[5] = bk: Q.bk constant over j -> cancels in softmax
  const float* Wv    = (const float*)d_in[6];
  const float* bv    = (const float*)d_in[7];
  const float* Wo    = (const float*)d_in[8];
  const float* bo    = (const float*)d_in[9];
  const float* gamma = (const float*)d_in[10];
  const float* beta  = (const float*)d_in[11];

  float* ws      = (float*)d_ws;
  u32*   MvT     = (u32*)ws;                 // 131072 u32
  float* bvoSum  = ws + 131072;              // 512 f32
  float* qkP     = ws + 131584;              // 4 x 262144 f32
  u32*   wp      = (u32*)(ws + 1180160);     // 131072 u32

  k_L1<<<578, 256, 0, stream>>>(x, Wq, bq, Wk, Wv, bv, Wo, bo, MvT, bvoSum, qkP);
  k2_attn<<<512, 256, 0, stream>>>(pair, qkP, wp);
  k_L3<<<64, 256, 0, stream>>>(wp, MvT, bvoSum, x, gamma, beta, (float*)d_out);
}

// Round 8
// 30.414 us; speedup vs baseline: 9.1177x; 2.4491x over previous
//
#include <hip/hip_runtime.h>
#include <hip/hip_bf16.h>
#include <stdint.h>

// B=2, L=256, CB=64, D=512, H=8, HD=64. BI = B*L = 512.
// Pipeline (5 launches; graph gaps ~1us, fixed harness overhead ~17us):
//   K0: MkT[hc][e] bf16 (pre-scaled 0.125), MvT[f][hc] bf16, Cb[hc] f32 (pre-scaled),
//       bvoP[8][512] f32   (MFMA, round-5 proven body)
//   G1: qk[bi][hc] bf16 = x @ Mk_s + Cb  (tile 32x32, 256 blocks, K=512 in 4 chunks)
//   K2: per (b,i): pair staged once -> scores MFMA (qk loaded directly as bf16 frags)
//       -> softmax (no max-sub) -> wp MFMA -> shfl-pack bf16 wp  (round-5 body)
//   G2: GP[bi][f] f32 = wp @ Mv  (tile 32x32, 256 blocks, K=512, single slice)
//   K4: LayerNorm(GP + bo + sum_h bvoP + x)
//
// ws (f32 offsets): MkT@0 (131072 u32) | MvT@131072 | Cb@262144 | bvoP@262656 |
//   qk@266752 (131072 u32) | wp@397824 (131072 u32) | GP@528896 (262144 f32)

using u32   = unsigned int;
using s8bf  = __attribute__((ext_vector_type(8))) short;
using f32x4 = __attribute__((ext_vector_type(4))) float;

union U4 { uint4 u; s8bf v; };

__device__ __forceinline__ u32 pack2(float a, float b) {
  __hip_bfloat162 h2 = __float22bfloat162_rn(make_float2(a, b));
  union { __hip_bfloat162 h; u32 u; } cv; cv.h = h2; return cv.u;
}
__device__ __forceinline__ ushort bf16r(float f) {
  u32 u = __float_as_uint(f);
  return (ushort)((u + 0x7fffu + ((u >> 16) & 1u)) >> 16);
}
__device__ __forceinline__ float ubf(ushort s) {
  return __uint_as_float(((u32)s) << 16);
}

// ---------------- K0: weight prep (MFMA bf16, round-5 body) ----------------
__global__ __launch_bounds__(256) void k0_prep(
    const float* __restrict__ Wq, const float* __restrict__ bq,
    const float* __restrict__ Wk, const float* __restrict__ Wv,
    const float* __restrict__ Wo, const float* __restrict__ bv,
    u32* __restrict__ MkT, u32* __restrict__ MvT,
    float* __restrict__ Cb, float* __restrict__ bvoP) {
  __shared__ ushort LA[64 * 72];
  __shared__ ushort LB[64 * 72];
  __shared__ float bvec[64];
  const int t = threadIdx.x;
  const int bid = blockIdx.x;
  const bool isMk = bid < 64;
  const int sub = isMk ? bid : bid - 64;
  const int h = sub >> 3;
  const int tile = (sub & 7) * 64;

  {
    int row = t >> 2, q = t & 3;
    const float* Arow = isMk ? (Wq + (size_t)(tile + row) * 512 + h * 64)
                             : (Wv + (size_t)row * 512 + h * 64);
    #pragma unroll
    for (int i = 0; i < 4; ++i) {
      int d0 = q * 4 + i * 16;
      float4 v = *(const float4*)(Arow + d0);
      *(uint2*)&LA[row * 72 + d0] = make_uint2(pack2(v.x, v.y), pack2(v.z, v.w));
    }
  }
  if (isMk) {
    int row = t >> 2, q = t & 3;
    const float* Brow = Wk + (size_t)row * 512 + h * 64;
    #pragma unroll
    for (int i = 0; i < 4; ++i) {
      int d0 = q * 4 + i * 16;
      float4 v = *(const float4*)(Brow + d0);
      *(uint2*)&LB[row * 72 + d0] = make_uint2(pack2(v.x, v.y), pack2(v.z, v.w));
    }
  } else {
    int d = t >> 2, q = t & 3;
    const float* Brow = Wo + (size_t)(h * 64 + d) * 512 + tile;
    #pragma unroll
    for (int i = 0; i < 4; ++i) {
      int f0 = q * 4 + i * 16;
      float4 v = *(const float4*)(Brow + f0);
      LB[(f0 + 0) * 72 + d] = bf16r(v.x);
      LB[(f0 + 1) * 72 + d] = bf16r(v.y);
      LB[(f0 + 2) * 72 + d] = bf16r(v.z);
      LB[(f0 + 3) * 72 + d] = bf16r(v.w);
    }
  }
  if (t < 16) {
    const float* bsrc = isMk ? bq : bv;
    float4 v = *(const float4*)&bsrc[h * 64 + t * 4];
    bvec[t * 4 + 0] = v.x; bvec[t * 4 + 1] = v.y;
    bvec[t * 4 + 2] = v.z; bvec[t * 4 + 3] = v.w;
  }
  __syncthreads();

  const int lane = t & 63, w = t >> 6;
  const int lr = lane & 15, lg = lane >> 4;
  f32x4 acc[4] = {};
  #pragma unroll
  for (int kk = 0; kk < 2; ++kk) {
    U4 a; a.u = *(const uint4*)&LA[(w * 16 + lr) * 72 + kk * 32 + lg * 8];
    #pragma unroll
    for (int nt = 0; nt < 4; ++nt) {
      U4 b; b.u = *(const uint4*)&LB[(nt * 16 + lr) * 72 + kk * 32 + lg * 8];
      acc[nt] = __builtin_amdgcn_mfma_f32_16x16x32_bf16(a.v, b.v, acc[nt], 0, 0, 0);
    }
  }
  if (isMk) {
    #pragma unroll
    for (int nt = 0; nt < 4; ++nt) {
      int hc = h * 64 + nt * 16 + lr;
      int e0 = tile + w * 16 + lg * 4;
      uint2 o = make_uint2(pack2(acc[nt][0] * 0.125f, acc[nt][1] * 0.125f),
                           pack2(acc[nt][2] * 0.125f, acc[nt][3] * 0.125f));
      *(uint2*)&MkT[(size_t)hc * 256 + (e0 >> 1)] = o;
    }
    if ((sub & 7) == 0 && t < 64) {
      float s = 0.f;
      #pragma unroll 16
      for (int d = 0; d < 64; ++d) s += bvec[d] * ubf(LB[t * 72 + d]);
      Cb[h * 64 + t] = s * 0.125f;
    }
  } else {
    #pragma unroll
    for (int nt = 0; nt < 4; ++nt) {
      int f = tile + nt * 16 + lr;
      int hc0 = h * 64 + w * 16 + lg * 4;
      uint2 o = make_uint2(pack2(acc[nt][0], acc[nt][1]),
                           pack2(acc[nt][2], acc[nt][3]));
      *(uint2*)&MvT[(size_t)f * 256 + (hc0 >> 1)] = o;
    }
    if (t < 64) {
      float s = 0.f;
      #pragma unroll 16
      for (int d = 0; d < 64; ++d) s += bvec[d] * ubf(LB[t * 72 + d]);
      bvoP[h * 512 + tile + t] = s;
    }
  }
}

// ---------------- G1: qk bf16 = x @ Mk_s + Cb, tile 32x32, K=512 ----------------
// grid (16 hc-tiles, 16 bi-tiles) = 256 blocks
__global__ __launch_bounds__(256) void k_g1(
    const float* __restrict__ x, const u32* __restrict__ MkT,
    const float* __restrict__ Cb, u32* __restrict__ qk) {
  __shared__ ushort As[32 * 136];
  __shared__ ushort Bs[32 * 136];
  const int t = threadIdx.x;
  const int n0 = blockIdx.x * 32;   // hc
  const int m0 = blockIdx.y * 32;   // bi
  const int lane = t & 63, w = t >> 6;
  const int lr = lane & 15, lg = lane >> 4;
  const int mh = w & 1, nh = w >> 1;
  const int row = t >> 3, q = t & 7;
  f32x4 acc = {0.f, 0.f, 0.f, 0.f};
  for (int kc = 0; kc < 4; ++kc) {
    { // A: x rows m0..+32, cols kc*128..+128, fp32 -> bf16 (16 f32/thread)
      const float* xp = x + (size_t)(m0 + row) * 512 + kc * 128 + q * 16;
      float4 v0 = *(const float4*)xp,       v1 = *(const float4*)(xp + 4);
      float4 v2 = *(const float4*)(xp + 8), v3 = *(const float4*)(xp + 12);
      *(uint4*)&As[row * 136 + q * 16] =
          make_uint4(pack2(v0.x, v0.y), pack2(v0.z, v0.w),
                     pack2(v1.x, v1.y), pack2(v1.z, v1.w));
      *(uint4*)&As[row * 136 + q * 16 + 8] =
          make_uint4(pack2(v2.x, v2.y), pack2(v2.z, v2.w),
                     pack2(v3.x, v3.y), pack2(v3.z, v3.w));
    }
    { // B: MkT rows n0..+32, u32 cols kc*64..+64 (8 u32/thread)
      const uint4* B4 = (const uint4*)MkT + (size_t)(n0 + row) * 64 + kc * 16 + q * 2;
      *(uint4*)&Bs[row * 136 + q * 16]     = B4[0];
      *(uint4*)&Bs[row * 136 + q * 16 + 8] = B4[1];
    }
    __syncthreads();
    #pragma unroll
    for (int kk = 0; kk < 4; ++kk) {
      U4 a; a.u = *(const uint4*)&As[(mh * 16 + lr) * 136 + kk * 32 + lg * 8];
      U4 b; b.u = *(const uint4*)&Bs[(nh * 16 + lr) * 136 + kk * 32 + lg * 8];
      acc = __builtin_amdgcn_mfma_f32_16x16x32_bf16(a.v, b.v, acc, 0, 0, 0);
    }
    __syncthreads();
  }
  const int n = n0 + nh * 16 + lr;
  const float cb = Cb[n];
  float v[4], prt[4];
  #pragma unroll
  for (int r = 0; r < 4; ++r) {
    v[r] = acc[r] + cb;
    prt[r] = __shfl_xor(v[r], 1, 64);
  }
  if ((lane & 1) == 0) {
    #pragma unroll
    for (int r = 0; r < 4; ++r)
      qk[(size_t)(m0 + mh * 16 + lg * 4 + r) * 256 + (n >> 1)] = pack2(v[r], prt[r]);
  }
}

// ---------------- K2: scores -> softmax -> wp (round-5 body, bf16 qk) ----------------
__global__ __launch_bounds__(256) void k2_attn(
    const float* __restrict__ pair, const u32* __restrict__ qk,
    u32* __restrict__ wpg) {
  __shared__ u32 PuU[256 * 36];
  __shared__ u32 PtU[64 * 132];
  __shared__ float redz[16][4];
  const int t = threadIdx.x, bi = blockIdx.x;
  const int lane = t & 63, w = t >> 6;
  const int lr = lane & 15, lg = lane >> 4;
  const float* pr = pair + (size_t)bi * 16384;

  #pragma unroll
  for (int r = 0; r < 8; ++r) {
    int task = t + 256 * r;
    int jp = task >> 4, cq = task & 15;
    const float* p0 = pr + (size_t)(2 * jp) * 64 + cq * 4;
    float4 a = *(const float4*)p0;
    float4 b = *(const float4*)(p0 + 64);
    *(uint2*)&PuU[(2 * jp) * 36 + cq * 2]     = make_uint2(pack2(a.x, a.y), pack2(a.z, a.w));
    *(uint2*)&PuU[(2 * jp + 1) * 36 + cq * 2] = make_uint2(pack2(b.x, b.y), pack2(b.z, b.w));
    int c = cq * 4;
    int col = jp ^ ((cq & 7) << 2);
    PtU[(c + 0) * 132 + col] = pack2(a.x, b.x);
    PtU[(c + 1) * 132 + col] = pack2(a.y, b.y);
    PtU[(c + 2) * 132 + col] = pack2(a.z, b.z);
    PtU[(c + 3) * 132 + col] = pack2(a.w, b.w);
  }

  // qk B-frags: direct bf16 loads (row bi = 256 u32 = 64 uint4)
  U4 bq0, bq1;
  bq0.u = make_uint4(0, 0, 0, 0); bq1.u = make_uint4(0, 0, 0, 0);
  if (lr < 8) {
    const uint4* qrow = (const uint4*)qk + (size_t)bi * 64 + lr * 8 + lg;
    bq0.u = qrow[0];
    bq1.u = qrow[4];
  }
  __syncthreads();

  f32x4 sc[4];
  #pragma unroll
  for (int jt = 0; jt < 4; ++jt) {
    int j0 = w * 64 + jt * 16;
    U4 a0, a1;
    a0.u = *(const uint4*)&PuU[(j0 + lr) * 36 + lg * 4];
    a1.u = *(const uint4*)&PuU[(j0 + lr) * 36 + 16 + lg * 4];
    f32x4 z = {0.f, 0.f, 0.f, 0.f};
    z = __builtin_amdgcn_mfma_f32_16x16x32_bf16(a0.v, bq0.v, z, 0, 0, 0);
    z = __builtin_amdgcn_mfma_f32_16x16x32_bf16(a1.v, bq1.v, z, 0, 0, 0);
    sc[jt] = z;
  }

  float ev[4][4];
  float es = 0.f;
  #pragma unroll
  for (int jt = 0; jt < 4; ++jt)
    #pragma unroll
    for (int r = 0; r < 4; ++r) { ev[jt][r] = __expf(sc[jt][r]); es += ev[jt][r]; }
  es += __shfl_xor(es, 16, 64);
  es += __shfl_xor(es, 32, 64);
  if (lane < 16) redz[lr][w] = es;
  __syncthreads();
  float4 zr = *(const float4*)&redz[lr][0];
  float rz = __builtin_amdgcn_rcpf(zr.x + zr.y + zr.z + zr.w);
  ushort* wb = (ushort*)PuU;
  #pragma unroll
  for (int jt = 0; jt < 4; ++jt) {
    int j0 = w * 64 + jt * 16 + lg * 4;
    uint2 o = make_uint2(pack2(ev[jt][0] * rz, ev[jt][1] * rz),
                         pack2(ev[jt][2] * rz, ev[jt][3] * rz));
    *(uint2*)&wb[lr * 264 + j0] = o;
  }
  __syncthreads();

  f32x4 wacc = {0.f, 0.f, 0.f, 0.f};
  const int c = w * 16 + lr;
  const int cswz = (c >> 2) & 7;
  #pragma unroll
  for (int ks = 0; ks < 8; ++ks) {
    U4 a; a.u = *(const uint4*)&wb[lr * 264 + ks * 32 + lg * 8];
    int g = ks * 4 + lg;
    U4 b; b.u = *(const uint4*)&PtU[c * 132 + ((g ^ cswz) << 2)];
    wacc = __builtin_amdgcn_mfma_f32_16x16x32_bf16(a.v, b.v, wacc, 0, 0, 0);
  }
  float prt[4];
  #pragma unroll
  for (int r = 0; r < 4; ++r) prt[r] = __shfl_xor(wacc[r], 1, 64);
  if (lane < 32 && (lane & 1) == 0) {
    #pragma unroll
    for (int r = 0; r < 4; ++r) {
      int h = lg * 4 + r;
      wpg[(size_t)bi * 256 + h * 32 + (c >> 1)] = pack2(wacc[r], prt[r]);
    }
  }
}

// ---------------- G2: GP f32 = wp @ Mv, tile 32x32, K=512 ----------------
// grid (16 f-tiles, 16 bi-tiles) = 256 blocks
__global__ __launch_bounds__(256) void k_g2(
    const u32* __restrict__ wp, const u32* __restrict__ MvT,
    float* __restrict__ GP) {
  __shared__ ushort As[32 * 136];
  __shared__ ushort Bs[32 * 136];
  const int t = threadIdx.x;
  const int n0 = blockIdx.x * 32;   // f
  const int m0 = blockIdx.y * 32;   // bi
  const int lane = t & 63, w = t >> 6;
  const int lr = lane & 15, lg = lane >> 4;
  const int mh = w & 1, nh = w >> 1;
  const int row = t >> 3, q = t & 7;
  f32x4 acc = {0.f, 0.f, 0.f, 0.f};
  for (int kc = 0; kc < 4; ++kc) {
    {
      const uint4* A4 = (const uint4*)wp + (size_t)(m0 + row) * 64 + kc * 16 + q * 2;
      *(uint4*)&As[row * 136 + q * 16]     = A4[0];
      *(uint4*)&As[row * 136 + q * 16 + 8] = A4[1];
      const uint4* B4 = (const uint4*)MvT + (size_t)(n0 + row) * 64 + kc * 16 + q * 2;
      *(uint4*)&Bs[row * 136 + q * 16]     = B4[0];
      *(uint4*)&Bs[row * 136 + q * 16 + 8] = B4[1];
    }
    __syncthreads();
    #pragma unroll
    for (int kk = 0; kk < 4; ++kk) {
      U4 a; a.u = *(const uint4*)&As[(mh * 16 + lr) * 136 + kk * 32 + lg * 8];
      U4 b; b.u = *(const uint4*)&Bs[(nh * 16 + lr) * 136 + kk * 32 + lg * 8];
      acc = __builtin_amdgcn_mfma_f32_16x16x32_bf16(a.v, b.v, acc, 0, 0, 0);
    }
    __syncthreads();
  }
  const int n = n0 + nh * 16 + lr;
  #pragma unroll
  for (int r = 0; r < 4; ++r)
    GP[(size_t)(m0 + mh * 16 + lg * 4 + r) * 512 + n] = acc[r];
}

// ---------------- K4: residual + biases + LayerNorm ----------------
__global__ __launch_bounds__(256) void k4_ln(
    const float* __restrict__ GP, const float* __restrict__ bvoP,
    const float* __restrict__ bo, const float* __restrict__ x,
    const float* __restrict__ gamma, const float* __restrict__ beta,
    float* __restrict__ out) {
  __shared__ float red[2][4];
  const int t = threadIdx.x, bi = blockIdx.x;
  const int f = t * 2;
  const size_t base = (size_t)bi * 512 + f;
  float2 y2 = *(const float2*)&GP[base];
  float2 xv = *(const float2*)&x[base];
  float2 bv2 = *(const float2*)&bo[f];
  y2.x += xv.x + bv2.x; y2.y += xv.y + bv2.y;
  #pragma unroll
  for (int h = 0; h < 8; ++h) {
    float2 bp = *(const float2*)&bvoP[h * 512 + f];
    y2.x += bp.x; y2.y += bp.y;
  }
  float s = y2.x + y2.y;
  float q = y2.x * y2.x + y2.y * y2.y;
  for (int o = 32; o; o >>= 1) { s += __shfl_xor(s, o, 64); q += __shfl_xor(q, o, 64); }
  const int wv = t >> 6, lane = t & 63;
  if (lane == 0) { red[0][wv] = s; red[1][wv] = q; }
  __syncthreads();
  float S = red[0][0] + red[0][1] + red[0][2] + red[0][3];
  float Qs = red[1][0] + red[1][1] + red[1][2] + red[1][3];
  float mu = S * (1.f / 512.f);
  float var = Qs * (1.f / 512.f) - mu * mu;
  float rstd = rsqrtf(var + 1e-5f);
  float2 gm = *(const float2*)&gamma[f];
  float2 bt = *(const float2*)&beta[f];
  float2 o2;
  o2.x = (y2.x - mu) * rstd * gm.x + bt.x;
  o2.y = (y2.y - mu) * rstd * gm.y + bt.y;
  *(float2*)&out[base] = o2;
}

extern "C" void kernel_launch(void* const* d_in, const int* in_sizes, int n_in,
                              void* d_out, int out_size, void* d_ws, size_t ws_size,
                              hipStream_t stream) {
  (void)in_sizes; (void)n_in; (void)out_size; (void)ws_size;
  const float* x     = (const float*)d_in[0];
  const float* pair  = (const float*)d_in[1];
  const float* Wq    = (const float*)d_in[2];
  const float* bq    = (const float*)d_in[3];
  const float* Wk    = (const float*)d_in[4];
  // d_in[5] = bk: Q.bk constant over j -> cancels in softmax
  const float* Wv    = (const float*)d_in[6];
  const float* bv    = (const float*)d_in[7];
  const float* Wo    = (const float*)d_in[8];
  const float* bo    = (const float*)d_in[9];
  const float* gamma = (const float*)d_in[10];
  const float* beta  = (const float*)d_in[11];

  float* ws   = (float*)d_ws;
  u32* MkT    = (u32*)ws;
  u32* MvT    = (u32*)ws + 131072;
  float* Cb   = ws + 262144;
  float* bvoP = ws + 262656;
  u32* qk     = (u32*)(ws + 266752);
  u32* wp     = (u32*)(ws + 397824);
  float* GP   = ws + 528896;

  k0_prep<<<128, 256, 0, stream>>>(Wq, bq, Wk, Wv, Wo, bv, MkT, MvT, Cb, bvoP);
  k_g1<<<dim3(16, 16), 256, 0, stream>>>(x, MkT, Cb, qk);
  k2_attn<<<512, 256, 0, stream>>>(pair, qk, wp);
  k_g2<<<dim3(16, 16), 256, 0, stream>>>(wp, MvT, GP);
  k4_ln<<<512, 256, 0, stream>>>(GP, bvoP, bo, x, gamma, beta, (float*)d_out);
}